// Round 11
// baseline (34.863 us; speedup 1.0000x reference)
//
#include <hip/hip_runtime.h>
#include <math.h>

#define NPTS 16384
#define DIM  24
#define ESIG 65536
#define ERND 32768
#define THRESH 2.0f
#define LDSS 36      // 72 B LDS row stride: worst-case 2-way banking on b128 (free)
#define NBLK 2080    // 64*65/2 triangular 256x256 tile blocks
#define EBLK 192     // 128 signal + 64 random edge blocks

typedef __attribute__((ext_vector_type(8))) short bf16x8;
typedef __attribute__((ext_vector_type(4))) float f32x4;

__device__ __forceinline__ unsigned short f2bf(float x) {
    unsigned int u = __float_as_uint(x);
    unsigned int r = u + 0x7fffu + ((u >> 16) & 1u);
    return (unsigned short)(r >> 16);
}

__device__ __forceinline__ float min3f(float a, float b, float c) {
    return fminf(fminf(a, b), c);   // fuses to v_min3_f32
}

__device__ __forceinline__ float wave_reduce(float v) {
#pragma unroll
    for (int off = 32; off > 0; off >>= 1)
        v += __shfl_down(v, off, 64);
    return v;
}

__device__ __forceinline__ float edge_d2(const float* __restrict__ emb, int a, int b) {
    const float4* ra = reinterpret_cast<const float4*>(emb + (size_t)a * DIM);
    const float4* rb = reinterpret_cast<const float4*>(emb + (size_t)b * DIM);
    float d2 = 0.f;
#pragma unroll
    for (int k = 0; k < 6; ++k) {
        float4 va = ra[k], vb = rb[k];
        float dx = va.x - vb.x, dy = va.y - vb.y;
        float dz = va.z - vb.z, dw = va.w - vb.w;
        d2 += dx * dx; d2 += dy * dy; d2 += dz * dz; d2 += dw * dw;
    }
    return d2;
}

// ONE kernel. blocks [0,128): signal edges; [128,192): random edges;
// [192, 192+2080): knn 256x256 triangular tiles.
__global__ __launch_bounds__(512) void fused_kernel(
    const float* __restrict__ emb, const int* __restrict__ sedge,
    const int* __restrict__ redge, const int* __restrict__ pid,
    float* __restrict__ out)
{
    __shared__ short lA[256 * LDSS];
    __shared__ short lB[256 * LDSS];
    __shared__ float red[8];

    const int b = blockIdx.x, t = threadIdx.x;
    const int lane = t & 63, wid = t >> 6;

    if (b < EBLK) {
        // ---------------- edge blocks ----------------
        float val;
        if (b < 128) {
            int e = b * 512 + t;
            val = (edge_d2(emb, sedge[e], sedge[ESIG + e]) + 1e-12f) * (1.f / ESIG);
        } else {
            int e = (b - 128) * 512 + t;
            int a = redge[e], bj = redge[ERND + e];
            val = 0.f;
            if (pid[a] != pid[bj]) {
                float d = sqrtf(edge_d2(emb, a, bj) + 1e-12f);
                float h = 1.f - d;
                if (h > 0.f) val = h * h * (1.f / ERND);
            }
        }
        float w = wave_reduce(val);
        if (lane == 0) red[wid] = w;
        __syncthreads();
        if (t == 0) {
            float s = red[0] + red[1] + red[2] + red[3]
                    + red[4] + red[5] + red[6] + red[7];
            atomicAdd(out, s);
        }
        return;
    }

    // ---------------- knn tile block: 256x256, bi <= bj ----------------
    // C(bi) = bi*(129-bi)/2 ; bj = bi + (id - C(bi))
    const int id = b - EBLK;
    int bi = (int)((129.0f - sqrtf(16641.0f - 8.0f * (float)id)) * 0.5f);
    while (bi * (129 - bi) / 2 > id) --bi;
    while ((bi + 1) * (129 - (bi + 1)) / 2 <= id) ++bi;
    const int bj = bi + (id - bi * (129 - bi) / 2);
    const int p0 = bi * 256, q0 = bj * 256;

    // stage: each thread converts ONE emb row into an augmented bf16 LDS row.
    //   A row i: [-2*E_i (24), sq_i, 1, 0...]   B row j: [E_j (24), 1, sq_j, 0...]
    //   dot(A_i, B_j) = sq_i + sq_j - 2 E_i.E_j = d^2(i,j)
    {
        const bool isA = t < 256;
        const int g = isA ? (p0 + t) : (q0 + t - 256);
        const float4* rp = reinterpret_cast<const float4*>(emb + (size_t)g * DIM);
        float v[24];
        float s = 0.f;
#pragma unroll
        for (int k = 0; k < 6; ++k) {
            float4 q = rp[k];
            v[4*k+0] = q.x; v[4*k+1] = q.y; v[4*k+2] = q.z; v[4*k+3] = q.w;
            s += q.x*q.x + q.y*q.y + q.z*q.z + q.w*q.w;
        }
        union { unsigned short u[32]; int4 q[4]; } rowu;
        const float m = isA ? -2.f : 1.f;
#pragma unroll
        for (int k = 0; k < 24; ++k) rowu.u[k] = f2bf(m * v[k]);
        unsigned short sqb = f2bf(s);
        rowu.u[24] = isA ? sqb : (unsigned short)0x3F80;
        rowu.u[25] = isA ? (unsigned short)0x3F80 : sqb;
#pragma unroll
        for (int k = 26; k < 32; ++k) rowu.u[k] = 0;
        short* dst = isA ? &lA[t * LDSS] : &lB[(t - 256) * LDSS];
#pragma unroll
        for (int k = 0; k < 4; ++k)
            *reinterpret_cast<int4*>(dst + k * 8) = rowu.q[k];
    }
    __syncthreads();

    // 8 waves as 2x4 grid: wave rows [wr*128,+128) x cols [wc*64,+64),
    // processed as two 64-row halves reusing the accumulator registers.
    const int wr = wid >> 2, wc = wid & 3;
    const int lrow = lane & 15, lkb = (lane >> 4) * 8;

    bf16x8 bfr[4];
#pragma unroll
    for (int c = 0; c < 4; ++c)
        bfr[c] = *reinterpret_cast<const bf16x8*>(
            &lB[(wc * 64 + c * 16 + lrow) * LDSS + lkb]);

    const f32x4 zero = {0.f, 0.f, 0.f, 0.f};
    float lacc = 0.f;

#pragma unroll 1
    for (int half = 0; half < 2; ++half) {
        const int rbase = wr * 128 + half * 64;

        bf16x8 af[4];
#pragma unroll
        for (int r = 0; r < 4; ++r)
            af[r] = *reinterpret_cast<const bf16x8*>(
                &lA[(rbase + r * 16 + lrow) * LDSS + lkb]);

        f32x4 acc[4][4];
#pragma unroll
        for (int r = 0; r < 4; ++r)
#pragma unroll
            for (int c = 0; c < 4; ++c)
                acc[r][c] = __builtin_amdgcn_mfma_f32_16x16x32_bf16(af[r], bfr[c], zero, 0, 0, 0);

        // min over the 64 d^2 values this lane holds (min3 trees)
        float tm[16];
#pragma unroll
        for (int r = 0; r < 4; ++r)
#pragma unroll
            for (int c = 0; c < 4; ++c)
                tm[r * 4 + c] = fminf(min3f(acc[r][c][0], acc[r][c][1], acc[r][c][2]),
                                      acc[r][c][3]);
        float m0 = min3f(tm[0], tm[1], tm[2]);
        float m1 = min3f(tm[3], tm[4], tm[5]);
        float m2 = min3f(tm[6], tm[7], tm[8]);
        float m3 = min3f(tm[9], tm[10], tm[11]);
        float m4 = min3f(tm[12], tm[13], tm[14]);
        float mn = fminf(min3f(min3f(m0, m1, m2), m3, m4), tm[15]);

        if (mn < THRESH) {   // diagonal cells / true near-pairs only
#pragma unroll
            for (int r = 0; r < 4; ++r)
#pragma unroll
                for (int c = 0; c < 4; ++c)
#pragma unroll
                    for (int e = 0; e < 4; ++e) {
                        if (acc[r][c][e] < THRESH) {
                            int i = p0 + rbase + r * 16 + (lane >> 4) * 4 + e;
                            int j = q0 + wc * 64 + c * 16 + (lane & 15);
                            if (i < j && pid[i] != pid[j]) {
                                float d = sqrtf(fmaxf(edge_d2(emb, i, j), 0.f) + 1e-12f);
                                if (d < 1.f) { float h = 1.f - d; lacc += h * h; }
                            }
                        }
                    }
        }
    }

    if (__any(lacc != 0.f)) {
        float wsum = wave_reduce(lacc);
        if (lane == 0) atomicAdd(out, wsum * (2.f / NPTS));
    }
}

extern "C" void kernel_launch(void* const* d_in, const int* in_sizes, int n_in,
                              void* d_out, int out_size, void* d_ws, size_t ws_size,
                              hipStream_t stream) {
    const float* emb   = (const float*)d_in[0];
    const int*   sedge = (const int*)d_in[1];
    const int*   redge = (const int*)d_in[2];
    const int*   pid   = (const int*)d_in[3];
    float* out = (float*)d_out;

    hipMemsetAsync(out, 0, sizeof(float), stream);
    fused_kernel<<<EBLK + NBLK, 512, 0, stream>>>(emb, sedge, redge, pid, out);
}

// Round 12
// 28.309 us; speedup vs baseline: 1.2315x; 1.2315x over previous
//
#include <hip/hip_runtime.h>
#include <math.h>

#define NPTS 16384
#define DIM  24
#define KPAD 32
#define ESIG 65536
#define ERND 32768
#define THRESH 2.0f
#define LDSS 36      // 72 B LDS row stride: row-banks walk all 16 even banks -> 2-way max (free)
#define CAP  8192

typedef __attribute__((ext_vector_type(8))) short bf16x8;
typedef __attribute__((ext_vector_type(4))) float f32x4;

// ws layout:
//   float sigP[256]; float rndP[128]; int cnt[4]; int cand[2*CAP];
//   ushort Ab[16384*32]; ushort Bb[16384*32];

__device__ __forceinline__ unsigned short f2bf(float x) {
    unsigned int u = __float_as_uint(x);
    unsigned int r = u + 0x7fffu + ((u >> 16) & 1u);
    return (unsigned short)(r >> 16);
}

__device__ __forceinline__ float min3f(float a, float b, float c) {
    return fminf(fminf(a, b), c);   // fuses to v_min3_f32
}

__device__ __forceinline__ float wave_reduce(float v) {
#pragma unroll
    for (int off = 32; off > 0; off >>= 1)
        v += __shfl_down(v, off, 64);
    return v;
}

__device__ __forceinline__ void block_reduce_store(float v, float* slot) {
    __shared__ float red[8];
    int lane = threadIdx.x & 63;
    int wid  = threadIdx.x >> 6;
    v = wave_reduce(v);
    if (lane == 0) red[wid] = v;
    __syncthreads();
    if (threadIdx.x == 0) {
        float s = 0.f;
        int nw = blockDim.x >> 6;
        for (int w = 0; w < nw; ++w) s += red[w];
        *slot = s;
    }
}

__device__ __forceinline__ float edge_d2(const float* __restrict__ emb, int a, int b) {
    const float4* ra = reinterpret_cast<const float4*>(emb + (size_t)a * DIM);
    const float4* rb = reinterpret_cast<const float4*>(emb + (size_t)b * DIM);
    float d2 = 0.f;
#pragma unroll
    for (int k = 0; k < 6; ++k) {
        float4 va = ra[k], vb = rb[k];
        float dx = va.x - vb.x, dy = va.y - vb.y;
        float dz = va.z - vb.z, dw = va.w - vb.w;
        d2 += dx * dx; d2 += dy * dy; d2 += dz * dz; d2 += dw * dw;
    }
    return d2;
}

// blocks [0,64): prep Ab/Bb rows; [64,320): signal edges; [320,448): random edges
__global__ __launch_bounds__(256) void fused_pre_kernel(
    const float* __restrict__ emb, const int* __restrict__ sedge,
    const int* __restrict__ redge, const int* __restrict__ pid,
    unsigned short* __restrict__ Ab, unsigned short* __restrict__ Bb,
    float* __restrict__ sigP, float* __restrict__ rndP, int* __restrict__ cnt)
{
    int b = blockIdx.x, t = threadIdx.x;
    if (b < 64) {
        if (b == 0 && t == 0) cnt[0] = 0;
        int i = b * 256 + t;
        const float4* rp = reinterpret_cast<const float4*>(emb + (size_t)i * DIM);
        float v[24];
        float s = 0.f;
#pragma unroll
        for (int k = 0; k < 6; ++k) {
            float4 q = rp[k];
            v[4*k+0] = q.x; v[4*k+1] = q.y; v[4*k+2] = q.z; v[4*k+3] = q.w;
            s += q.x*q.x + q.y*q.y + q.z*q.z + q.w*q.w;
        }
        union { unsigned short u[32]; int4 q[4]; } a, bb;
#pragma unroll
        for (int k = 0; k < 24; ++k) { a.u[k] = f2bf(-2.f * v[k]); bb.u[k] = f2bf(v[k]); }
        a.u[24] = f2bf(s);   a.u[25] = f2bf(1.f);
        bb.u[24] = f2bf(1.f); bb.u[25] = f2bf(s);
#pragma unroll
        for (int k = 26; k < 32; ++k) { a.u[k] = 0; bb.u[k] = 0; }
        int4* pa = reinterpret_cast<int4*>(Ab + (size_t)i * KPAD);
        int4* pb = reinterpret_cast<int4*>(Bb + (size_t)i * KPAD);
#pragma unroll
        for (int k = 0; k < 4; ++k) { pa[k] = a.q[k]; pb[k] = bb.q[k]; }
    } else if (b < 320) {
        int eb = b - 64;
        int e = eb * 256 + t;
        float d2 = edge_d2(emb, sedge[e], sedge[ESIG + e]) + 1e-12f;
        block_reduce_store(d2, &sigP[eb]);
    } else {
        int eb = b - 320;
        int e = eb * 256 + t;
        int a = redge[e], bj = redge[ERND + e];
        float val = 0.f;
        if (pid[a] != pid[bj]) {
            float d = sqrtf(edge_d2(emb, a, bj) + 1e-12f);
            float h = 1.f - d;
            if (h > 0.f) val = h * h;
        }
        block_reduce_store(val, &rndP[eb]);
    }
}

// One-shot 256x128 tile per block; 8 waves (4x2), each wave 64x64 = 16 MFMA.
// Upper-triangle blocks only (bj >= 2*bi); emit candidates with i<j (weight 2 later).
__global__ __launch_bounds__(512) void knn_mfma_kernel(
    const unsigned short* __restrict__ Ab, const unsigned short* __restrict__ Bb,
    int* __restrict__ cnt, int* __restrict__ cand)
{
    const int bi = blockIdx.x;          // 64 i-panels of 256 rows
    const int bj = blockIdx.y;          // 128 j-panels of 128 cols
    if (bj < 2 * bi) return;            // no i<j pairs in this block

    __shared__ short lB[128 * LDSS];
    const int t  = threadIdx.x;
    const int i0 = bi * 256, j0 = bj * 128;

    // stage B panel: 128 rows x 64 B, one int4 per thread (coalesced)
    {
        int row = t >> 2, q = t & 3;
        int4 v = *reinterpret_cast<const int4*>(Bb + (size_t)(j0 + row) * KPAD + q * 8);
        *reinterpret_cast<int4*>(&lB[row * LDSS + q * 8]) = v;
    }

    const int wid = t >> 6, lane = t & 63;
    const int wr = wid >> 1, wc = wid & 1;          // 4x2 wave grid
    const int lrow = lane & 15, lkb = (lane >> 4) * 8;

    // A fragments: direct global, 1 KB contiguous per instruction per wave
    bf16x8 af[4];
#pragma unroll
    for (int r = 0; r < 4; ++r)
        af[r] = *reinterpret_cast<const bf16x8*>(
            Ab + (size_t)(i0 + wr * 64 + r * 16 + lrow) * KPAD + lkb);

    __syncthreads();

    bf16x8 bfr[4];
#pragma unroll
    for (int c = 0; c < 4; ++c)
        bfr[c] = *reinterpret_cast<const bf16x8*>(
            &lB[(wc * 64 + c * 16 + lrow) * LDSS + lkb]);

    const f32x4 zero = {0.f, 0.f, 0.f, 0.f};
    f32x4 acc[4][4];
#pragma unroll
    for (int r = 0; r < 4; ++r)
#pragma unroll
        for (int c = 0; c < 4; ++c)
            acc[r][c] = __builtin_amdgcn_mfma_f32_16x16x32_bf16(af[r], bfr[c], zero, 0, 0, 0);

    // min over the 64 d^2 values this lane holds (min3 trees)
    float tm[16];
#pragma unroll
    for (int r = 0; r < 4; ++r)
#pragma unroll
        for (int c = 0; c < 4; ++c)
            tm[r * 4 + c] = fminf(min3f(acc[r][c][0], acc[r][c][1], acc[r][c][2]),
                                  acc[r][c][3]);
    float m0 = min3f(tm[0], tm[1], tm[2]);
    float m1 = min3f(tm[3], tm[4], tm[5]);
    float m2 = min3f(tm[6], tm[7], tm[8]);
    float m3 = min3f(tm[9], tm[10], tm[11]);
    float m4 = min3f(tm[12], tm[13], tm[14]);
    float mn = fminf(min3f(min3f(m0, m1, m2), m3, m4), tm[15]);

    if (mn < THRESH) {   // fires only for diagonal cells / true near-pairs
#pragma unroll
        for (int r = 0; r < 4; ++r)
#pragma unroll
            for (int c = 0; c < 4; ++c)
#pragma unroll
                for (int e = 0; e < 4; ++e) {
                    if (acc[r][c][e] < THRESH) {
                        int i = i0 + wr * 64 + r * 16 + (lane >> 4) * 4 + e;
                        int j = j0 + wc * 64 + c * 16 + (lane & 15);
                        if (i < j) {
                            int slot = atomicAdd(cnt, 1);
                            if (slot < CAP) {
                                cand[2 * slot]     = i;
                                cand[2 * slot + 1] = j;
                            }
                        }
                    }
                }
    }
}

// exact fp32 recheck of candidates (weight 2: i<j only) + final reduction
__global__ __launch_bounds__(256) void finalize_kernel(
    const float* __restrict__ emb, const int* __restrict__ pid,
    const int* __restrict__ cnt, const int* __restrict__ cand,
    const float* __restrict__ sigP, const float* __restrict__ rndP,
    float* __restrict__ out)
{
    int t = threadIdx.x;
    int n = cnt[0];
    if (n > CAP) n = CAP;
    float ca = 0.f;
    for (int k = t; k < n; k += 256) {
        int i = cand[2 * k], j = cand[2 * k + 1];
        if (pid[i] != pid[j]) {
            float d = sqrtf(fmaxf(edge_d2(emb, i, j), 0.f) + 1e-12f);
            if (d < 1.f) { float h = 1.f - d; ca += h * h; }
        }
    }
    float v = ca * (2.f / NPTS) + sigP[t] * (1.f / ESIG);
    if (t < 128) v += rndP[t] * (1.f / ERND);
    block_reduce_store(v, out);
}

extern "C" void kernel_launch(void* const* d_in, const int* in_sizes, int n_in,
                              void* d_out, int out_size, void* d_ws, size_t ws_size,
                              hipStream_t stream) {
    const float* emb   = (const float*)d_in[0];
    const int*   sedge = (const int*)d_in[1];
    const int*   redge = (const int*)d_in[2];
    const int*   pid   = (const int*)d_in[3];
    float* out = (float*)d_out;

    float* sigP = (float*)d_ws;                       // 256
    float* rndP = sigP + 256;                         // 128
    int*   cnt  = (int*)(rndP + 128);                 // 4 (padded)
    int*   cand = cnt + 4;                            // 2*CAP
    unsigned short* Ab = (unsigned short*)(cand + 2 * CAP);   // 16384*32
    unsigned short* Bb = Ab + (size_t)NPTS * KPAD;            // 16384*32

    fused_pre_kernel<<<448, 256, 0, stream>>>(emb, sedge, redge, pid, Ab, Bb, sigP, rndP, cnt);
    knn_mfma_kernel<<<dim3(64, 128), 512, 0, stream>>>(Ab, Bb, cnt, cand);
    finalize_kernel<<<1, 256, 0, stream>>>(emb, pid, cnt, cand, sigP, rndP, out);
}